// Round 3
// baseline (327.499 us; speedup 1.0000x reference)
//
#include <hip/hip_runtime.h>

#define B_  4
#define N_  2048
#define H_  16
#define HD_ 1024

typedef short  bf16x8 __attribute__((ext_vector_type(8)));
typedef float  f32x4  __attribute__((ext_vector_type(4)));

static __device__ __forceinline__ unsigned short f2bf(float f) {
    unsigned int u = __builtin_bit_cast(unsigned int, f);
    u += 0x7FFFu + ((u >> 16) & 1u);   // RNE
    return (unsigned short)(u >> 16);
}

static __device__ __forceinline__ unsigned rne_hi(float f) {
    unsigned u = __builtin_bit_cast(unsigned, f);
    return u + 0x7FFFu + ((u >> 16) & 1u);   // bf16 in bits [31:16]
}
// pack two floats -> (bf16(hi)<<16)|bf16(lo) : 2x(bfe+add3) + v_perm
static __device__ __forceinline__ unsigned f2bf2pack(float lo, float hi) {
    return __builtin_amdgcn_perm(rne_hi(hi), rne_hi(lo), 0x07060302u);
}

// ---------------- projection via MFMA, one phase per block ----------------
// grid (N/64, H, B*3); z = b*3 + p
// q,k out: [b,h,n,64] bf16 (q pre-scaled by 0.125*log2e); v out transposed [b,h,64,n]
__global__ __launch_bounds__(256) void proj_kernel(
    const float* __restrict__ Qv, const float* __restrict__ Kv,
    const float* __restrict__ Vv, const float* __restrict__ WQ,
    const float* __restrict__ WK, const float* __restrict__ WV,
    unsigned short* __restrict__ qs, unsigned short* __restrict__ ks,
    unsigned short* __restrict__ vt)
{
    __shared__ __align__(16) unsigned short xb[64][72];
    __shared__ __align__(16) unsigned short Wb[64][72];
    __shared__ __align__(16) unsigned short sb[64][72];

    const int tid  = threadIdx.x;
    const int wq   = tid >> 6;
    const int lane = tid & 63;
    const int l15  = lane & 15;
    const int quad = lane >> 4;

    const int i0 = blockIdx.x * 64;
    const int h  = blockIdx.y;
    const int bz = blockIdx.z;
    const int b  = bz / 3;
    const int p  = bz - b * 3;

    const size_t inbase = ((size_t)b * N_ + i0) * HD_ + h * 64;
    const size_t bh     = (size_t)b * H_ + h;

    const float* W   = (p == 0) ? WQ : (p == 1) ? WK : WV;
    const float* inp = ((p == 0) ? Qv : (p == 1) ? Kv : Vv) + inbase;

    for (int v = tid; v < 1024; v += 256) {
        int tok = v >> 4, c4 = (v & 15) * 4;
        float4 f = *reinterpret_cast<const float4*>(inp + (size_t)tok * HD_ + c4);
        uint2 u;
        u.x = f2bf2pack(f.x, f.y);
        u.y = f2bf2pack(f.z, f.w);
        *reinterpret_cast<uint2*>(&xb[tok][c4]) = u;
        float4 g = *reinterpret_cast<const float4*>(W + (size_t)v * 4);
        uint2 w2;
        w2.x = f2bf2pack(g.x, g.y);
        w2.y = f2bf2pack(g.z, g.w);
        *reinterpret_cast<uint2*>(&Wb[tok][c4]) = w2;
    }
    __syncthreads();

    // A = x[token][c], B = W[out][c]  ->  D[token][out]
    bf16x8 ax[2];
    #pragma unroll
    for (int kh = 0; kh < 2; ++kh)
        ax[kh] = *reinterpret_cast<const bf16x8*>(&xb[wq * 16 + l15][kh * 32 + quad * 8]);

    f32x4 C[4];
    #pragma unroll
    for (int t = 0; t < 4; ++t) {
        C[t] = f32x4{0.f, 0.f, 0.f, 0.f};
        #pragma unroll
        for (int kh = 0; kh < 2; ++kh) {
            bf16x8 bw = *reinterpret_cast<const bf16x8*>(&Wb[t * 16 + l15][kh * 32 + quad * 8]);
            C[t] = __builtin_amdgcn_mfma_f32_16x16x32_bf16(ax[kh], bw, C[t], 0, 0, 0);
        }
    }

    if (p < 2) {
        const float scl = (p == 0) ? 0.180336880f : 1.f;  // 0.125 * log2(e) folded into q
        #pragma unroll
        for (int t = 0; t < 4; ++t)
            #pragma unroll
            for (int r = 0; r < 4; ++r)
                sb[wq * 16 + quad * 4 + r][t * 16 + l15] = f2bf(C[t][r] * scl);
        __syncthreads();
        unsigned short* dst = ((p == 0) ? qs : ks) + ((size_t)bh * N_ + i0) * 64;
        for (int v = tid; v < 512; v += 256) {
            int row = v >> 3, c0 = (v & 7) * 8;
            *reinterpret_cast<uint4*>(dst + (size_t)row * 64 + c0) =
                *reinterpret_cast<const uint4*>(&sb[row][c0]);
        }
    } else {
        // store transposed: sb[d][token], cols contiguous in r -> packed b64 writes
        #pragma unroll
        for (int t = 0; t < 4; ++t) {
            uint2 u;
            u.x = f2bf2pack(C[t][0], C[t][1]);
            u.y = f2bf2pack(C[t][2], C[t][3]);
            *reinterpret_cast<uint2*>(&sb[t * 16 + l15][wq * 16 + quad * 4]) = u;
        }
        __syncthreads();
        unsigned short* vdst = vt + (size_t)bh * 64 * N_ + i0;
        for (int v = tid; v < 512; v += 256) {
            int d = v >> 3, c0 = (v & 7) * 8;
            *reinterpret_cast<uint4*>(vdst + (size_t)d * N_ + c0) =
                *reinterpret_cast<const uint4*>(&sb[d][c0]);
        }
    }
}

// ---------------- flash attention, fixed-max softmax (log2 domain) ----------------
// grid: (N/64, B*H), block 256 (4 waves, 16 q-rows each)
__global__ __launch_bounds__(256) void attn_kernel(
    const unsigned short* __restrict__ qs, const unsigned short* __restrict__ ks,
    const unsigned short* __restrict__ vt, const int* __restrict__ maskp,
    float* __restrict__ out)
{
    __shared__ __align__(16) unsigned short Ks[64][72];
    __shared__ __align__(16) unsigned short Vt[64][72];   // [d][kv]
    __shared__ __align__(16) unsigned short Ps[4][16][72];
    __shared__ float kb[64];

    const int tid  = threadIdx.x;
    const int wq   = tid >> 6;
    const int lane = tid & 63;
    const int l15  = lane & 15;
    const int quad = lane >> 4;

    const int i0 = blockIdx.x * 64;
    const int bh = blockIdx.y;
    const int b  = bh >> 4;
    const int h  = bh & 15;

    // staging swizzle: row' = (row&~7) | ((row&7)^granule) -> uniform bank classes
    const int sg  = tid & 7;                    // 16B granule 0..7
    const int rsw = ((tid >> 3) & 24) | (((tid >> 3) & 7) ^ sg);
    const int c0s = sg * 8;                     // shorts

    // Q fragments straight from global (one row = 128B; 16B/lane chunks)
    const unsigned short* qrow = qs + ((size_t)bh * N_ + i0 + wq * 16 + l15) * 64;
    bf16x8 aq[2];
    aq[0] = *reinterpret_cast<const bf16x8*>(qrow + quad * 8);
    aq[1] = *reinterpret_cast<const bf16x8*>(qrow + 32 + quad * 8);

    // query mask per accumulator row (row = quad*4 + r)
    float qm[4];
    #pragma unroll
    for (int r = 0; r < 4; ++r)
        qm[r] = maskp[b * N_ + i0 + wq * 16 + quad * 4 + r] ? 1.f : 0.f;

    // ones B-fragment: column 0 of B all-ones -> D[:,0] = row sums
    bf16x8 bones;
    {
        short onev = (l15 == 0) ? (short)0x3F80 : (short)0;
        #pragma unroll
        for (int j = 0; j < 8; ++j) bones[j] = onev;
    }

    f32x4 O[4];
    f32x4 L = f32x4{0.f, 0.f, 0.f, 0.f};
    #pragma unroll
    for (int t = 0; t < 4; ++t) O[t] = f32x4{0.f, 0.f, 0.f, 0.f};

    const unsigned short* kbase = ks + (size_t)bh * N_ * 64;
    const unsigned short* vbase = vt + (size_t)bh * 64 * N_;

    for (int kv0 = 0; kv0 < N_; kv0 += 64) {
        __syncthreads();                       // prior iter's readers done
        #pragma unroll
        for (int it = 0; it < 2; ++it) {
            int r = rsw + it * 32;
            *reinterpret_cast<uint4*>(&Ks[r][c0s]) =
                *reinterpret_cast<const uint4*>(kbase + (size_t)(kv0 + r) * 64 + c0s);
            *reinterpret_cast<uint4*>(&Vt[r][c0s]) =
                *reinterpret_cast<const uint4*>(vbase + (size_t)r * N_ + kv0 + c0s);
        }
        if (tid < 64) kb[tid] = maskp[b * N_ + kv0 + tid] ? 0.f : -1e30f;
        __syncthreads();

        // S = q @ k^T  (16 rows x 64 cols per wave), log2-domain scores
        f32x4 S[4];
        #pragma unroll
        for (int t = 0; t < 4; ++t) {
            S[t] = f32x4{0.f, 0.f, 0.f, 0.f};
            #pragma unroll
            for (int kh = 0; kh < 2; ++kh) {
                bf16x8 bk = *reinterpret_cast<const bf16x8*>(&Ks[t * 16 + l15][kh * 32 + quad * 8]);
                S[t] = __builtin_amdgcn_mfma_f32_16x16x32_bf16(aq[kh], bk, S[t], 0, 0, 0);
            }
        }

        float kbl[4];
        #pragma unroll
        for (int t = 0; t < 4; ++t) kbl[t] = kb[t * 16 + l15];

        // fixed-max softmax in log2 domain (q pre-scaled by log2e):
        // masked key -> s=-1e30 -> exp2=0; masked query row -> s=0 -> uniform.
        #pragma unroll
        for (int t = 0; t < 4; ++t)
            #pragma unroll
            for (int r = 0; r < 4; ++r) {
                float s = (S[t][r] + kbl[t]) * qm[r];
                Ps[wq][quad * 4 + r][t * 16 + l15] = f2bf(exp2f(s));
            }

        __builtin_amdgcn_s_waitcnt(0xC07F);     // lgkmcnt(0): same-wave LDS RAW

        bf16x8 ap[2];
        #pragma unroll
        for (int kh = 0; kh < 2; ++kh)
            ap[kh] = *reinterpret_cast<const bf16x8*>(&Ps[wq][l15][kh * 32 + quad * 8]);

        #pragma unroll
        for (int t = 0; t < 4; ++t) {
            #pragma unroll
            for (int kh = 0; kh < 2; ++kh) {
                bf16x8 bv = *reinterpret_cast<const bf16x8*>(&Vt[t * 16 + l15][kh * 32 + quad * 8]);
                O[t] = __builtin_amdgcn_mfma_f32_16x16x32_bf16(ap[kh], bv, O[t], 0, 0, 0);
            }
        }
        // row sums of P via ones-column MFMA (same bf16 P as numerator)
        #pragma unroll
        for (int kh = 0; kh < 2; ++kh)
            L = __builtin_amdgcn_mfma_f32_16x16x32_bf16(ap[kh], bones, L, 0, 0, 0);
    }

    // epilogue: l lives in lanes l15==0 (lane = quad*16), broadcast within quad-group
    float invl[4];
    #pragma unroll
    for (int r = 0; r < 4; ++r) {
        float l = __shfl(L[r], lane & 48);
        invl[r] = 1.f / l;
    }
    #pragma unroll
    for (int t = 0; t < 4; ++t)
        #pragma unroll
        for (int r = 0; r < 4; ++r) {
            int i = i0 + wq * 16 + quad * 4 + r;
            out[((size_t)b * N_ + i) * HD_ + h * 64 + t * 16 + l15] = O[t][r] * invl[r];
        }
}

extern "C" void kernel_launch(void* const* d_in, const int* in_sizes, int n_in,
                              void* d_out, int out_size, void* d_ws, size_t ws_size,
                              hipStream_t stream)
{
    const float* Qv  = (const float*)d_in[0];
    const float* Kv  = (const float*)d_in[1];
    const float* Vv  = (const float*)d_in[2];
    const float* WQ  = (const float*)d_in[3];
    const float* WK  = (const float*)d_in[4];
    const float* WV  = (const float*)d_in[5];
    const int*   msk = (const int*)d_in[6];
    float* out = (float*)d_out;

    const size_t per = (size_t)B_ * H_ * N_ * 64;   // 8.4M elems, bf16
    unsigned short* qsb = (unsigned short*)d_ws;
    unsigned short* ksb = qsb + per;
    unsigned short* vtb = ksb + per;

    proj_kernel<<<dim3(N_ / 64, H_, B_ * 3), 256, 0, stream>>>(Qv, Kv, Vv, WQ, WK, WV, qsb, ksb, vtb);
    attn_kernel<<<dim3(N_ / 64, B_ * H_), 256, 0, stream>>>(qsb, ksb, vtb, msk, out);
}

// Round 4
// 245.037 us; speedup vs baseline: 1.3365x; 1.3365x over previous
//
#include <hip/hip_runtime.h>

#define B_  4
#define N_  2048
#define H_  16
#define HD_ 1024

typedef short  bf16x8 __attribute__((ext_vector_type(8)));
typedef short  bf16x4 __attribute__((ext_vector_type(4)));
typedef float  f32x4  __attribute__((ext_vector_type(4)));

static __device__ __forceinline__ unsigned short f2bf(float f) {
    unsigned int u = __builtin_bit_cast(unsigned int, f);
    u += 0x7FFFu + ((u >> 16) & 1u);   // RNE
    return (unsigned short)(u >> 16);
}

static __device__ __forceinline__ unsigned rne_hi(float f) {
    unsigned u = __builtin_bit_cast(unsigned, f);
    return u + 0x7FFFu + ((u >> 16) & 1u);   // bf16 in bits [31:16]
}
// pack two floats -> (bf16(hi)<<16)|bf16(lo)
static __device__ __forceinline__ unsigned f2bf2pack(float lo, float hi) {
    return __builtin_amdgcn_perm(rne_hi(hi), rne_hi(lo), 0x07060302u);
}

// ---------------- projection via MFMA, one phase per block ----------------
// grid (N/64, H, B*3); z = b*3 + p
// q,k out: [b,h,n,64] bf16 (q pre-scaled by 0.125*log2e); v out transposed [b,h,64,n]
__global__ __launch_bounds__(256) void proj_kernel(
    const float* __restrict__ Qv, const float* __restrict__ Kv,
    const float* __restrict__ Vv, const float* __restrict__ WQ,
    const float* __restrict__ WK, const float* __restrict__ WV,
    unsigned short* __restrict__ qs, unsigned short* __restrict__ ks,
    unsigned short* __restrict__ vt)
{
    __shared__ __align__(16) unsigned short xb[64][72];
    __shared__ __align__(16) unsigned short Wb[64][72];
    __shared__ __align__(16) unsigned short sb[64][72];

    const int tid  = threadIdx.x;
    const int wq   = tid >> 6;
    const int lane = tid & 63;
    const int l15  = lane & 15;
    const int quad = lane >> 4;

    const int i0 = blockIdx.x * 64;
    const int h  = blockIdx.y;
    const int bz = blockIdx.z;
    const int b  = bz / 3;
    const int p  = bz - b * 3;

    const size_t inbase = ((size_t)b * N_ + i0) * HD_ + h * 64;
    const size_t bh     = (size_t)b * H_ + h;

    const float* W   = (p == 0) ? WQ : (p == 1) ? WK : WV;
    const float* inp = ((p == 0) ? Qv : (p == 1) ? Kv : Vv) + inbase;

    for (int v = tid; v < 1024; v += 256) {
        int tok = v >> 4, c4 = (v & 15) * 4;
        float4 f = *reinterpret_cast<const float4*>(inp + (size_t)tok * HD_ + c4);
        uint2 u;
        u.x = f2bf2pack(f.x, f.y);
        u.y = f2bf2pack(f.z, f.w);
        *reinterpret_cast<uint2*>(&xb[tok][c4]) = u;
        float4 g = *reinterpret_cast<const float4*>(W + (size_t)v * 4);
        uint2 w2;
        w2.x = f2bf2pack(g.x, g.y);
        w2.y = f2bf2pack(g.z, g.w);
        *reinterpret_cast<uint2*>(&Wb[tok][c4]) = w2;
    }
    __syncthreads();

    bf16x8 ax[2];
    #pragma unroll
    for (int kh = 0; kh < 2; ++kh)
        ax[kh] = *reinterpret_cast<const bf16x8*>(&xb[wq * 16 + l15][kh * 32 + quad * 8]);

    f32x4 C[4];
    #pragma unroll
    for (int t = 0; t < 4; ++t) {
        C[t] = f32x4{0.f, 0.f, 0.f, 0.f};
        #pragma unroll
        for (int kh = 0; kh < 2; ++kh) {
            bf16x8 bw = *reinterpret_cast<const bf16x8*>(&Wb[t * 16 + l15][kh * 32 + quad * 8]);
            C[t] = __builtin_amdgcn_mfma_f32_16x16x32_bf16(ax[kh], bw, C[t], 0, 0, 0);
        }
    }

    if (p < 2) {
        const float scl = (p == 0) ? 0.180336880f : 1.f;  // 0.125 * log2(e)
        #pragma unroll
        for (int t = 0; t < 4; ++t)
            #pragma unroll
            for (int r = 0; r < 4; ++r)
                sb[wq * 16 + quad * 4 + r][t * 16 + l15] = f2bf(C[t][r] * scl);
        __syncthreads();
        unsigned short* dst = ((p == 0) ? qs : ks) + ((size_t)bh * N_ + i0) * 64;
        for (int v = tid; v < 512; v += 256) {
            int row = v >> 3, c0 = (v & 7) * 8;
            *reinterpret_cast<uint4*>(dst + (size_t)row * 64 + c0) =
                *reinterpret_cast<const uint4*>(&sb[row][c0]);
        }
    } else {
        #pragma unroll
        for (int t = 0; t < 4; ++t) {
            uint2 u;
            u.x = f2bf2pack(C[t][0], C[t][1]);
            u.y = f2bf2pack(C[t][2], C[t][3]);
            *reinterpret_cast<uint2*>(&sb[t * 16 + l15][wq * 16 + quad * 4]) = u;
        }
        __syncthreads();
        unsigned short* vdst = vt + (size_t)bh * 64 * N_ + i0;
        for (int v = tid; v < 512; v += 256) {
            int d = v >> 3, c0 = (v & 7) * 8;
            *reinterpret_cast<uint4*>(vdst + (size_t)d * N_ + c0) =
                *reinterpret_cast<const uint4*>(&sb[d][c0]);
        }
    }
}

// ---------------- transposed flash attention ----------------
// S^T = K Q^T, O^T = V^T P^T. P never touches LDS: the S^T C-layout registers
// ARE the P B-fragment under the k-permutation sigma(k): j = {k5,k2,k4,k3,k1:0}.
// grid: (N/256, B*H), block 256 = 4 waves, each wave owns 64 q-rows.
__global__ __launch_bounds__(256, 2) void attn_kernel(
    const unsigned short* __restrict__ qs, const unsigned short* __restrict__ ks,
    const unsigned short* __restrict__ vt, const int* __restrict__ maskp,
    float* __restrict__ out)
{
    __shared__ __align__(16) unsigned short Ks[64][72];   // stride 36 dw: b128 reads uniform
    __shared__ __align__(16) unsigned short Vt[64][68];   // stride 34 dw: b64 reads conflict-free
    __shared__ float kb[64];

    const int tid  = threadIdx.x;
    const int w    = tid >> 6;
    const int lane = tid & 63;
    const int l15  = lane & 15;
    const int quad = lane >> 4;

    const int i0 = blockIdx.x * 256;
    const int bh = blockIdx.y;
    const int b  = bh >> 4;
    const int h  = bh & 15;
    const int qrow0 = i0 + w * 64;

    // Q fragments (B-operand) for 4 row-tiles, straight from global
    bf16x8 aq[4][2];
    float  qm[4];
    #pragma unroll
    for (int rt = 0; rt < 4; ++rt) {
        const unsigned short* qrow = qs + ((size_t)bh * N_ + qrow0 + rt * 16 + l15) * 64;
        aq[rt][0] = *reinterpret_cast<const bf16x8*>(qrow + quad * 8);
        aq[rt][1] = *reinterpret_cast<const bf16x8*>(qrow + 32 + quad * 8);
        qm[rt] = maskp[b * N_ + qrow0 + rt * 16 + l15] ? 1.f : 0.f;
    }

    bf16x8 aones;
    #pragma unroll
    for (int j = 0; j < 8; ++j) aones[j] = (short)0x3F80;

    f32x4 O[4][4];     // [rt][ct2] : O^T[d-block ct2][qrow-block rt]
    f32x4 L[4];
    #pragma unroll
    for (int rt = 0; rt < 4; ++rt) {
        L[rt] = f32x4{0.f, 0.f, 0.f, 0.f};
        #pragma unroll
        for (int c = 0; c < 4; ++c) O[rt][c] = f32x4{0.f, 0.f, 0.f, 0.f};
    }

    const unsigned short* kbase = ks + (size_t)bh * N_ * 64;
    const unsigned short* vbase = vt + (size_t)bh * 64 * N_;

    for (int kv0 = 0; kv0 < N_; kv0 += 64) {
        __syncthreads();
        // stage K rows [64][64] (b128, bank-uniform) and V^T rows (b64 pairs)
        #pragma unroll
        for (int it = 0; it < 2; ++it) {
            int idx = tid + it * 256;          // 0..511
            int r = idx >> 3, g = idx & 7;
            *reinterpret_cast<uint4*>(&Ks[r][g * 8]) =
                *reinterpret_cast<const uint4*>(kbase + (size_t)(kv0 + r) * 64 + g * 8);
        }
        #pragma unroll
        for (int it = 0; it < 4; ++it) {
            int idx = tid + it * 256;          // 0..1023, 8B chunks
            int r = idx >> 4, g2 = idx & 15;
            *reinterpret_cast<uint2*>(&Vt[r][g2 * 4]) =
                *reinterpret_cast<const uint2*>(vbase + (size_t)r * N_ + kv0 + g2 * 4);
        }
        if (tid < 64) kb[tid] = maskp[b * N_ + kv0 + tid] ? 0.f : -1e30f;
        __syncthreads();

        // K A-fragments (shared across all 4 rt) and V A-fragments
        bf16x8 ak[4][2];
        #pragma unroll
        for (int ct = 0; ct < 4; ++ct)
            #pragma unroll
            for (int kh = 0; kh < 2; ++kh)
                ak[ct][kh] = *reinterpret_cast<const bf16x8*>(&Ks[ct * 16 + l15][kh * 32 + quad * 8]);

        bf16x8 av[4][2];
        #pragma unroll
        for (int ct = 0; ct < 4; ++ct)
            #pragma unroll
            for (int kh = 0; kh < 2; ++kh) {
                bf16x4 lo = *reinterpret_cast<const bf16x4*>(&Vt[ct * 16 + l15][kh * 32 + quad * 4]);
                bf16x4 hi = *reinterpret_cast<const bf16x4*>(&Vt[ct * 16 + l15][kh * 32 + 16 + quad * 4]);
                av[ct][kh] = bf16x8{lo[0], lo[1], lo[2], lo[3], hi[0], hi[1], hi[2], hi[3]};
            }

        f32x4 kbv[4];
        #pragma unroll
        for (int ct = 0; ct < 4; ++ct)
            kbv[ct] = *reinterpret_cast<const f32x4*>(&kb[ct * 16 + quad * 4]);

        #pragma unroll
        for (int rt = 0; rt < 4; ++rt) {
            // S^T: lane holds S[qrow=rt*16+l15][j=16ct+4q+r]
            f32x4 S[4];
            #pragma unroll
            for (int ct = 0; ct < 4; ++ct) {
                S[ct] = f32x4{0.f, 0.f, 0.f, 0.f};
                #pragma unroll
                for (int kh = 0; kh < 2; ++kh)
                    S[ct] = __builtin_amdgcn_mfma_f32_16x16x32_bf16(ak[ct][kh], aq[rt][kh], S[ct], 0, 0, 0);
            }
            // masked exp2 (q pre-scaled by log2e); pack directly into P B-fragments
            unsigned pk[4][2];
            #pragma unroll
            for (int ct = 0; ct < 4; ++ct) {
                float e0 = __builtin_amdgcn_exp2f((S[ct][0] + kbv[ct][0]) * qm[rt]);
                float e1 = __builtin_amdgcn_exp2f((S[ct][1] + kbv[ct][1]) * qm[rt]);
                float e2 = __builtin_amdgcn_exp2f((S[ct][2] + kbv[ct][2]) * qm[rt]);
                float e3 = __builtin_amdgcn_exp2f((S[ct][3] + kbv[ct][3]) * qm[rt]);
                pk[ct][0] = f2bf2pack(e0, e1);
                pk[ct][1] = f2bf2pack(e2, e3);
            }
            bf16x8 ap[2];
            #pragma unroll
            for (int kh = 0; kh < 2; ++kh) {
                uint4 u = uint4{pk[2 * kh][0], pk[2 * kh][1], pk[2 * kh + 1][0], pk[2 * kh + 1][1]};
                ap[kh] = __builtin_bit_cast(bf16x8, u);
            }
            // row-sums: D[m][n=qrow] = sum_k P — every lane gets its own qrow's L
            #pragma unroll
            for (int kh = 0; kh < 2; ++kh)
                L[rt] = __builtin_amdgcn_mfma_f32_16x16x32_bf16(aones, ap[kh], L[rt], 0, 0, 0);
            // O^T += V^T P^T
            #pragma unroll
            for (int ct = 0; ct < 4; ++ct)
                #pragma unroll
                for (int kh = 0; kh < 2; ++kh)
                    O[rt][ct] = __builtin_amdgcn_mfma_f32_16x16x32_bf16(av[ct][kh], ap[kh], O[rt][ct], 0, 0, 0);
        }
    }

    // epilogue: lane (q,l15) holds O^T[d=16ct+4q+r][qrow=rt*16+l15]; L[rt] components all equal
    #pragma unroll
    for (int rt = 0; rt < 4; ++rt) {
        float inv = 1.f / L[rt][0];
        float* orow = out + ((size_t)b * N_ + qrow0 + rt * 16 + l15) * HD_ + h * 64 + quad * 4;
        #pragma unroll
        for (int ct = 0; ct < 4; ++ct)
            #pragma unroll
            for (int r = 0; r < 4; ++r)
                orow[ct * 16 + r] = O[rt][ct][r] * inv;
    }
}

extern "C" void kernel_launch(void* const* d_in, const int* in_sizes, int n_in,
                              void* d_out, int out_size, void* d_ws, size_t ws_size,
                              hipStream_t stream)
{
    const float* Qv  = (const float*)d_in[0];
    const float* Kv  = (const float*)d_in[1];
    const float* Vv  = (const float*)d_in[2];
    const float* WQ  = (const float*)d_in[3];
    const float* WK  = (const float*)d_in[4];
    const float* WV  = (const float*)d_in[5];
    const int*   msk = (const int*)d_in[6];
    float* out = (float*)d_out;

    const size_t per = (size_t)B_ * H_ * N_ * 64;   // 8.4M elems, bf16
    unsigned short* qsb = (unsigned short*)d_ws;
    unsigned short* ksb = qsb + per;
    unsigned short* vtb = ksb + per;

    proj_kernel<<<dim3(N_ / 64, H_, B_ * 3), 256, 0, stream>>>(Qv, Kv, Vv, WQ, WK, WV, qsb, ksb, vtb);
    attn_kernel<<<dim3(N_ / 256, B_ * H_), 256, 0, stream>>>(qsb, ksb, vtb, msk, out);
}